// Round 18
// baseline (1405.807 us; speedup 1.0000x reference)
//
#include <hip/hip_runtime.h>
#include <math.h>

#define DD   512
#define NTOT 65536
#define RR   64
#define NB   2
#define EPSV 1e-6f

typedef unsigned short u16;
typedef __attribute__((ext_vector_type(8))) short bf16x8;
typedef __attribute__((ext_vector_type(8))) unsigned short us8;
typedef __attribute__((ext_vector_type(4))) unsigned short us4;
typedef __attribute__((ext_vector_type(4))) float f32x4;

__device__ inline u16 f2bf(float f) {
    union { float f; unsigned u; } x; x.f = f;
    unsigned r = x.u + 0x7FFFu + ((x.u >> 16) & 1u);   // RNE (no NaN here)
    return (u16)(r >> 16);
}
__device__ inline float bf2f(u16 h) {
    union { unsigned u; float f; } x; x.u = ((unsigned)h) << 16;
    return x.f;
}
__device__ inline u16 clamp1(u16 h) {
    short t = (short)h;
    return (u16)(t < (short)0x3586 ? (short)0x3586 : t);
}
__device__ inline bf16x8 clampbf8(bf16x8 v) {
#pragma unroll
    for (int i = 0; i < 8; ++i) {
        short t = v[i];
        v[i] = (t < (short)0x3586) ? (short)0x3586 : t;
    }
    return v;
}

#define MFMA16(a, b, c) __builtin_amdgcn_mfma_f32_16x16x32_bf16((a), (b), (c), 0, 0, 0)

// ---------------------------------------------------------------------------
// convert_x (r15-proven): x fp32 [s][d][n] -> xd bf16 clamped [s][d][n]
// (us4 stores) + xTr bf16 RAW [s][n][d]. grid (NTOT/64, DD/64, NB). Pad 66.
// ---------------------------------------------------------------------------
__global__ __launch_bounds__(256) void convert_x_kernel(const float* __restrict__ x,
                                                        u16* __restrict__ xd,
                                                        u16* __restrict__ xTr) {
    int s = blockIdx.z, d0 = blockIdx.y * 64, n0 = blockIdx.x * 64;
    const float* xp = x + ((size_t)s * DD + d0) * NTOT + n0;
    u16* xdp = xd + ((size_t)s * DD + d0) * NTOT + n0;
    u16* xtr = xTr + ((size_t)s * NTOT + n0) * DD + d0;
    __shared__ u16 L[64][66];
    int tid = threadIdx.x;
#pragma unroll
    for (int k = 0; k < 4; ++k) {
        int f4 = tid + k * 256;
        int dr = f4 >> 4, c4 = (f4 & 15) * 4;
        float4 v = *(const float4*)&xp[(size_t)dr * NTOT + c4];
        u16 h0 = f2bf(v.x), h1 = f2bf(v.y), h2 = f2bf(v.z), h3 = f2bf(v.w);
        us4 pc;
        pc[0] = clamp1(h0); pc[1] = clamp1(h1);
        pc[2] = clamp1(h2); pc[3] = clamp1(h3);
        *(us4*)&xdp[(size_t)dr * NTOT + c4] = pc;
        L[dr][c4 + 0] = h0; L[dr][c4 + 1] = h1;
        L[dr][c4 + 2] = h2; L[dr][c4 + 3] = h3;
    }
    __syncthreads();
#pragma unroll
    for (int k = 0; k < 2; ++k) {
        int f8 = tid + k * 256;
        int nr = f8 >> 3, d8 = (f8 & 7) * 8;
        us8 wr;
#pragma unroll
        for (int i = 0; i < 8; ++i) wr[i] = L[d8 + i][nr];
        *(us8*)&xtr[(size_t)nr * DD + d8] = wr;
    }
}

// ---------------------------------------------------------------------------
// bnorm (r13-proven + zero duty): per batch, column-l2-normalize src -> b0,
// b_bf, bT_bf, BtB (MFMA gram); also zeroes ctc+numB for the next step.
// grid (NB), 1024 thr.
// ---------------------------------------------------------------------------
__global__ __launch_bounds__(1024) void bnorm_kernel(const float* __restrict__ src,
                                                     float* __restrict__ b0,
                                                     u16* __restrict__ b_bf,
                                                     u16* __restrict__ bT_bf,
                                                     u16* __restrict__ btb_bf,
                                                     float* __restrict__ ctcZ,
                                                     float* __restrict__ nBZ) {
    int s = blockIdx.x, tid = threadIdx.x;
    int r = tid & 63, grp = tid >> 6;
    const float* sp = src + (size_t)s * DD * RR;
    float* b0p = b0 + (size_t)s * DD * RR;
    u16* bbp = b_bf + (size_t)s * DD * RR;
    {
        float4 z4 = {0.f, 0.f, 0.f, 0.f};
        float* zc = ctcZ + (size_t)s * RR * RR;
        float* zn = nBZ + (size_t)s * DD * RR;
        *(float4*)&zc[tid * 4] = z4;
#pragma unroll
        for (int k = 0; k < 8; ++k)
            *(float4*)&zn[(tid + k * 1024) * 4] = z4;
    }
    __shared__ float part[16][64];
    __shared__ float invl[64];
    __shared__ __align__(16) u16 btl[64][520];
    float vv[32];
    float p = 0.f;
#pragma unroll
    for (int i = 0; i < 32; ++i) {
        vv[i] = sp[(grp * 32 + i) * 64 + r];
        p += vv[i] * vv[i];
    }
    part[grp][r] = p;
    __syncthreads();
    if (tid < 64) {
        float ss = 0.f;
#pragma unroll
        for (int k = 0; k < 16; ++k) ss += part[k][tid];
        invl[tid] = 1.f / fmaxf(sqrtf(ss), 1e-12f);
    }
    __syncthreads();
    float inv = invl[r];
#pragma unroll
    for (int i = 0; i < 32; ++i) {
        int d = grp * 32 + i;
        float v = vv[i] * inv;
        b0p[d * 64 + r] = v;
        u16 h = f2bf(v);
        bbp[d * 64 + r] = h;
        btl[r][d] = h;
    }
    __syncthreads();
    u16* btg = bT_bf + (size_t)s * RR * DD;
#pragma unroll
    for (int k = 0; k < 4; ++k) {
        int f8 = tid + k * 1024;
        int row = f8 >> 6, c8 = (f8 & 63) * 8;
        *(us8*)&btg[row * DD + c8] = *(const us8*)&btl[row][c8];
    }
    if (grp < 4) {
        int g = r >> 4, l15 = r & 15;
        f32x4 zero = {0.f, 0.f, 0.f, 0.f};
        f32x4 acc[4];
#pragma unroll
        for (int cs = 0; cs < 4; ++cs) acc[cs] = zero;
        for (int k0 = 0; k0 < DD; k0 += 32) {
            bf16x8 a = *(const bf16x8*)&btl[grp * 16 + l15][k0 + g * 8];
            bf16x8 b[4];
#pragma unroll
            for (int cs = 0; cs < 4; ++cs)
                b[cs] = *(const bf16x8*)&btl[cs * 16 + l15][k0 + g * 8];
#pragma unroll
            for (int cs = 0; cs < 4; ++cs) acc[cs] = MFMA16(a, b[cs], acc[cs]);
        }
        u16* op = btb_bf + (size_t)s * RR * RR;
#pragma unroll
        for (int cs = 0; cs < 4; ++cs)
#pragma unroll
            for (int e = 0; e < 4; ++e)
                op[(grp * 16 + g * 4 + e) * RR + cs * 16 + l15] = f2bf(acc[cs][e]);
    }
}

// ---------------------------------------------------------------------------
// init2_mfma (r17-proven): FUSED init-softmax + step 0, coalesced cTf write.
// grid (NTOT/128, NB), 256 thr.
// ---------------------------------------------------------------------------
__global__ __launch_bounds__(256) void init2_mfma_kernel(const u16* __restrict__ xT,
                                                         const u16* __restrict__ bT,
                                                         const u16* __restrict__ btbbf,
                                                         u16* __restrict__ cnb,
                                                         u16* __restrict__ cT) {
    int s = blockIdx.y;
    int n0 = blockIdx.x * 128;
    int tid = threadIdx.x;
    int w = tid >> 6, lane = tid & 63, g = lane >> 4, l15 = lane & 15;
    int nw = n0 + w * 32;
    const u16* xTp = xT + (size_t)s * NTOT * DD;
    const u16* bTp = bT + (size_t)s * RR * DD;
    const u16* bb = btbbf + (size_t)s * RR * RR;
    u16* cnp = cnb + (size_t)s * NTOT * RR;
    u16* cTp = cT + (size_t)s * RR * NTOT;
    __shared__ __align__(16) u16 CL[128][72];
    __shared__ __align__(16) u16 TL[64][132];

    f32x4 zero = {0.f, 0.f, 0.f, 0.f};
    f32x4 accR[4][2], accC[4][2];
#pragma unroll
    for (int rs = 0; rs < 4; ++rs)
#pragma unroll
        for (int ns = 0; ns < 2; ++ns) { accR[rs][ns] = zero; accC[rs][ns] = zero; }

    {
        bf16x8 aA[4], bA[2], aB[4], bB[2];
#pragma unroll
        for (int rs = 0; rs < 4; ++rs)
            aA[rs] = *(const bf16x8*)&bTp[(rs * 16 + l15) * DD + g * 8];
#pragma unroll
        for (int ns = 0; ns < 2; ++ns)
            bA[ns] = *(const bf16x8*)&xTp[(size_t)(nw + ns * 16 + l15) * DD + g * 8];
#pragma unroll
        for (int i = 0; i < 8; ++i) {
            int kB = i * 64 + 32;
#pragma unroll
            for (int rs = 0; rs < 4; ++rs)
                aB[rs] = *(const bf16x8*)&bTp[(rs * 16 + l15) * DD + kB + g * 8];
#pragma unroll
            for (int ns = 0; ns < 2; ++ns)
                bB[ns] = *(const bf16x8*)&xTp[(size_t)(nw + ns * 16 + l15) * DD + kB + g * 8];
#pragma unroll
            for (int ns = 0; ns < 2; ++ns) {
                bf16x8 bc = clampbf8(bA[ns]);
#pragma unroll
                for (int rs = 0; rs < 4; ++rs) {
                    accR[rs][ns] = MFMA16(aA[rs], bA[ns], accR[rs][ns]);
                    accC[rs][ns] = MFMA16(aA[rs], bc, accC[rs][ns]);
                }
            }
            int kA = (i < 7) ? i * 64 + 64 : i * 64;
#pragma unroll
            for (int rs = 0; rs < 4; ++rs)
                aA[rs] = *(const bf16x8*)&bTp[(rs * 16 + l15) * DD + kA + g * 8];
#pragma unroll
            for (int ns = 0; ns < 2; ++ns)
                bA[ns] = *(const bf16x8*)&xTp[(size_t)(nw + ns * 16 + l15) * DD + kA + g * 8];
#pragma unroll
            for (int ns = 0; ns < 2; ++ns) {
                bf16x8 bc = clampbf8(bB[ns]);
#pragma unroll
                for (int rs = 0; rs < 4; ++rs) {
                    accR[rs][ns] = MFMA16(aB[rs], bB[ns], accR[rs][ns]);
                    accC[rs][ns] = MFMA16(aB[rs], bc, accC[rs][ns]);
                }
            }
        }
    }

#pragma unroll
    for (int ns = 0; ns < 2; ++ns) {
        int nloc = w * 32 + ns * 16 + l15;
        float m = accR[0][ns][0];
#pragma unroll
        for (int rs = 0; rs < 4; ++rs)
#pragma unroll
            for (int e = 0; e < 4; ++e) m = fmaxf(m, accR[rs][ns][e]);
        m = fmaxf(m, __shfl_xor(m, 16));
        m = fmaxf(m, __shfl_xor(m, 32));
        float ev[4][4];
        float ssum = 0.f;
#pragma unroll
        for (int rs = 0; rs < 4; ++rs)
#pragma unroll
            for (int e = 0; e < 4; ++e) {
                ev[rs][e] = __expf(accR[rs][ns][e] - m);
                ssum += ev[rs][e];
            }
        ssum += __shfl_xor(ssum, 16);
        ssum += __shfl_xor(ssum, 32);
        float inv = 1.f / ssum;
#pragma unroll
        for (int rs = 0; rs < 4; ++rs) {
            us4 pack;
#pragma unroll
            for (int e = 0; e < 4; ++e) pack[e] = f2bf(ev[rs][e] * inv);
            *(us4*)&CL[nloc][rs * 16 + g * 4] = pack;
        }
    }
    __syncthreads();

    f32x4 accD[4][2];
#pragma unroll
    for (int rs = 0; rs < 4; ++rs)
#pragma unroll
        for (int ns = 0; ns < 2; ++ns) accD[rs][ns] = zero;
#pragma unroll
    for (int k0 = 0; k0 < 64; k0 += 32) {
        bf16x8 a[4], b[2];
#pragma unroll
        for (int rs = 0; rs < 4; ++rs)
            a[rs] = *(const bf16x8*)&bb[(rs * 16 + l15) * RR + k0 + g * 8];
#pragma unroll
        for (int ns = 0; ns < 2; ++ns)
            b[ns] = *(const bf16x8*)&CL[w * 32 + ns * 16 + l15][k0 + g * 8];
#pragma unroll
        for (int rs = 0; rs < 4; ++rs)
#pragma unroll
            for (int ns = 0; ns < 2; ++ns)
                accD[rs][ns] = MFMA16(a[rs], b[ns], accD[rs][ns]);
    }

#pragma unroll
    for (int ns = 0; ns < 2; ++ns) {
        int n = nw + ns * 16 + l15;
        int nloc = w * 32 + ns * 16 + l15;
#pragma unroll
        for (int rs = 0; rs < 4; ++rs) {
            us4 cf4 = *(const us4*)&CL[nloc][rs * 16 + g * 4];
            us4 pack;
#pragma unroll
            for (int e = 0; e < 4; ++e) {
                int r = rs * 16 + g * 4 + e;
                float cin = bf2f(cf4[e]);
                float v = cin * accC[rs][ns][e] / (accD[rs][ns][e] + EPSV);
                u16 h = f2bf(v);
                TL[r][nloc] = h;
                pack[e] = clamp1(h);
            }
            *(us4*)&cnp[(size_t)n * RR + rs * 16 + g * 4] = pack;
        }
    }
    __syncthreads();
#pragma unroll
    for (int k = 0; k < 4; ++k) {
        int f8 = tid + k * 256;
        int row = f8 >> 4, c8 = (f8 & 15) * 8;
        *(us8*)&cTp[(size_t)row * NTOT + n0 + c8] = *(const us8*)&TL[row][c8];
    }
}

// ---------------------------------------------------------------------------
// xtb_mfma (r17 + n-tile 64 for 2x TLP): den = BtB@cnb; T = bT@clamp(x);
// c = cnb*T/(den+EPS) -> TL->cTf (coalesced) and clamped cnb.
// grid (NTOT/64, NB) = 2048 blocks, 256 thr; wave w owns 16 n-rows.
// No atomics, no inter-block coupling -> pure TLP gain; ~-36 VGPR.
// ---------------------------------------------------------------------------
__global__ __launch_bounds__(256) void xtb_mfma_kernel(const u16* __restrict__ xT,
                                                       const u16* __restrict__ bT,
                                                       const u16* __restrict__ btbbf,
                                                       u16* __restrict__ cnb,
                                                       u16* __restrict__ cT) {
    int s = blockIdx.y;
    int n0 = blockIdx.x * 64;
    int tid = threadIdx.x;
    int w = tid >> 6, lane = tid & 63, g = lane >> 4, l15 = lane & 15;
    int nw = n0 + w * 16;
    const u16* xTp = xT + (size_t)s * NTOT * DD;
    const u16* bTp = bT + (size_t)s * RR * DD;
    const u16* bb = btbbf + (size_t)s * RR * RR;
    u16* cnp = cnb + (size_t)s * NTOT * RR;
    u16* cTp = cT + (size_t)s * RR * NTOT;
    __shared__ __align__(16) u16 TL[64][68];   // c-tile [r][n_local], pad 68

    f32x4 zero = {0.f, 0.f, 0.f, 0.f};
    f32x4 accD[4], accT[4];
#pragma unroll
    for (int rs = 0; rs < 4; ++rs) { accD[rs] = zero; accT[rs] = zero; }

    // den phase: K=64 over r'; cnb holds clamped prev c
#pragma unroll
    for (int k0 = 0; k0 < 64; k0 += 32) {
        bf16x8 a[4];
#pragma unroll
        for (int rs = 0; rs < 4; ++rs)
            a[rs] = *(const bf16x8*)&bb[(rs * 16 + l15) * RR + k0 + g * 8];
        bf16x8 b = *(const bf16x8*)&cnp[(size_t)(nw + l15) * RR + k0 + g * 8];
#pragma unroll
        for (int rs = 0; rs < 4; ++rs) accD[rs] = MFMA16(a[rs], b, accD[rs]);
    }

    // T phase: K=512, pipelined, in-loop clamp on raw xTr
    {
        bf16x8 aA[4], bA, aB[4], bB;
#pragma unroll
        for (int rs = 0; rs < 4; ++rs)
            aA[rs] = *(const bf16x8*)&bTp[(rs * 16 + l15) * DD + g * 8];
        bA = clampbf8(*(const bf16x8*)&xTp[(size_t)(nw + l15) * DD + g * 8]);
#pragma unroll
        for (int i = 0; i < 8; ++i) {
            int kB = i * 64 + 32;
#pragma unroll
            for (int rs = 0; rs < 4; ++rs)
                aB[rs] = *(const bf16x8*)&bTp[(rs * 16 + l15) * DD + kB + g * 8];
            bB = clampbf8(*(const bf16x8*)&xTp[(size_t)(nw + l15) * DD + kB + g * 8]);
#pragma unroll
            for (int rs = 0; rs < 4; ++rs) accT[rs] = MFMA16(aA[rs], bA, accT[rs]);
            int kA = (i < 7) ? i * 64 + 64 : i * 64;
#pragma unroll
            for (int rs = 0; rs < 4; ++rs)
                aA[rs] = *(const bf16x8*)&bTp[(rs * 16 + l15) * DD + kA + g * 8];
            bA = clampbf8(*(const bf16x8*)&xTp[(size_t)(nw + l15) * DD + kA + g * 8]);
#pragma unroll
            for (int rs = 0; rs < 4; ++rs) accT[rs] = MFMA16(aB[rs], bB, accT[rs]);
        }
    }

    // epilogue: cin from cnb (coalesced us4); c -> TL + clamped cnb.
    {
        int n = nw + l15;
        int nloc = w * 16 + l15;
#pragma unroll
        for (int rs = 0; rs < 4; ++rs) {
            us4 cin4 = *(const us4*)&cnp[(size_t)n * RR + rs * 16 + g * 4];
            us4 pack;
#pragma unroll
            for (int e = 0; e < 4; ++e) {
                int r = rs * 16 + g * 4 + e;
                float cin = bf2f(cin4[e]);
                float v = cin * accT[rs][e] / (accD[rs][e] + EPSV);
                u16 h = f2bf(v);
                TL[r][nloc] = h;
                pack[e] = clamp1(h);   // v>0 so clamp = max
            }
            *(us4*)&cnp[(size_t)n * RR + rs * 16 + g * 4] = pack;
        }
    }
    __syncthreads();
#pragma unroll
    for (int k = 0; k < 2; ++k) {
        int f8 = tid + k * 256;
        int row = f8 >> 3, c8 = (f8 & 7) * 8;
        *(us8*)&cTp[(size_t)row * NTOT + n0 + c8] = *(const us8*)&TL[row][c8];
    }
}

// ---------------------------------------------------------------------------
// step_gemm (r12-proven): dual-role packed dispatch. Blocks 0..255 = xtc body
// (ksplit 32, chunk 2048); blocks 256..383 = ctc body (chunk 512).
// grid (384, NB), 256 thr.
// ---------------------------------------------------------------------------
__global__ __launch_bounds__(256) void step_gemm_kernel(const u16* __restrict__ xd,
                                                        const u16* __restrict__ cT,
                                                        float* __restrict__ numB,
                                                        float* __restrict__ ctc) {
    int s = blockIdx.y;
    int bid = blockIdx.x;
    int tid = threadIdx.x;
    int w = tid >> 6, lane = tid & 63, g = lane >> 4, l15 = lane & 15;
    const u16* cTp = cT + (size_t)s * RR * NTOT;
    f32x4 zero = {0.f, 0.f, 0.f, 0.f};

    if (bid < 256) {
        int kbase = (bid >> 3) * 2048;
        int dtile = (bid & 7) * 64;
        const u16* arow =
            xd + (size_t)s * DD * NTOT + (size_t)(dtile + w * 16 + l15) * NTOT;
        f32x4 acc[4];
#pragma unroll
        for (int rs = 0; rs < 4; ++rs) acc[rs] = zero;

        bf16x8 aA, bA[4], aB, bB[4];
        aA = *(const bf16x8*)&arow[kbase + g * 8];
#pragma unroll
        for (int rs = 0; rs < 4; ++rs)
            bA[rs] = *(const bf16x8*)&cTp[(size_t)(rs * 16 + l15) * NTOT + kbase + g * 8];
#pragma unroll
        for (int i = 0; i < 32; ++i) {
            int kB = kbase + i * 64 + 32;
            aB = *(const bf16x8*)&arow[kB + g * 8];
#pragma unroll
            for (int rs = 0; rs < 4; ++rs)
                bB[rs] = *(const bf16x8*)&cTp[(size_t)(rs * 16 + l15) * NTOT + kB + g * 8];
#pragma unroll
            for (int rs = 0; rs < 4; ++rs) acc[rs] = MFMA16(aA, bA[rs], acc[rs]);
            int kA = (i < 31) ? kbase + i * 64 + 64 : kbase;
            aA = *(const bf16x8*)&arow[kA + g * 8];
#pragma unroll
            for (int rs = 0; rs < 4; ++rs)
                bA[rs] = *(const bf16x8*)&cTp[(size_t)(rs * 16 + l15) * NTOT + kA + g * 8];
#pragma unroll
            for (int rs = 0; rs < 4; ++rs) acc[rs] = MFMA16(aB, bB[rs], acc[rs]);
        }
        float* op = numB + (size_t)s * DD * RR;
#pragma unroll
        for (int rs = 0; rs < 4; ++rs)
#pragma unroll
            for (int e = 0; e < 4; ++e)
                atomicAdd(&op[(dtile + w * 16 + g * 4 + e) * RR + rs * 16 + l15],
                          acc[rs][e]);
    } else {
        int kbase = (bid - 256) * 512;
        const u16* arow = cTp + (size_t)(w * 16 + l15) * NTOT;
        f32x4 acc[4];
#pragma unroll
        for (int cs = 0; cs < 4; ++cs) acc[cs] = zero;

        bf16x8 aA, bA[4], aB, bB[4];
        aA = *(const bf16x8*)&arow[kbase + g * 8];
#pragma unroll
        for (int cs = 0; cs < 4; ++cs)
            bA[cs] = *(const bf16x8*)&cTp[(size_t)(cs * 16 + l15) * NTOT + kbase + g * 8];
#pragma unroll
        for (int i = 0; i < 8; ++i) {
            int kB = kbase + i * 64 + 32;
            aB = *(const bf16x8*)&arow[kB + g * 8];
#pragma unroll
            for (int cs = 0; cs < 4; ++cs)
                bB[cs] = *(const bf16x8*)&cTp[(size_t)(cs * 16 + l15) * NTOT + kB + g * 8];
#pragma unroll
            for (int cs = 0; cs < 4; ++cs) acc[cs] = MFMA16(aA, bA[cs], acc[cs]);
            int kA = (i < 7) ? kbase + i * 64 + 64 : kbase;
            aA = *(const bf16x8*)&arow[kA + g * 8];
#pragma unroll
            for (int cs = 0; cs < 4; ++cs)
                bA[cs] = *(const bf16x8*)&cTp[(size_t)(cs * 16 + l15) * NTOT + kA + g * 8];
#pragma unroll
            for (int cs = 0; cs < 4; ++cs) acc[cs] = MFMA16(aB, bB[cs], acc[cs]);
        }
        float* op = ctc + (size_t)s * RR * RR;
#pragma unroll
        for (int cs = 0; cs < 4; ++cs)
#pragma unroll
            for (int e = 0; e < 4; ++e)
                atomicAdd(&op[(w * 16 + g * 4 + e) * RR + cs * 16 + l15], acc[cs][e]);
    }
}

// ---------------------------------------------------------------------------
// bupd_s (proven): b0 = max(b0*numB/(b0@CtC+EPS), EPS) in-place.
// grid (8, NB), 256 thr.
// ---------------------------------------------------------------------------
__global__ __launch_bounds__(256) void bupd_s_kernel(float* __restrict__ b0,
                                                     const float* __restrict__ numB,
                                                     const float* __restrict__ ctcG) {
    int s = blockIdx.y;
    int d0 = blockIdx.x * 64;
    float* bp = b0 + ((size_t)s * DD + d0) * RR;
    const float* np_ = numB + ((size_t)s * DD + d0) * RR;
    const float* cc = ctcG + (size_t)s * RR * RR;
    __shared__ __align__(16) float Bsh[64][68];
    __shared__ __align__(16) float Ct[64][68];
    int tid = threadIdx.x, tx = tid & 15, ty = tid >> 4;
#pragma unroll
    for (int k = 0; k < 16; ++k) {
        int idx = tid + k * 256;
        int r_ = idx >> 6, col = idx & 63;
        Bsh[r_][col] = bp[idx];
        Ct[r_][col] = cc[idx];
    }
    __syncthreads();
#pragma unroll
    for (int i = 0; i < 4; ++i) {
        int d = 4 * ty + i;
        float den[4] = {};
#pragma unroll
        for (int k = 0; k < 64; ++k) {
            float bv = Bsh[d][k];
            float4 ct = *(const float4*)&Ct[k][4 * tx];
            den[0] += bv * ct.x;
            den[1] += bv * ct.y;
            den[2] += bv * ct.z;
            den[3] += bv * ct.w;
        }
        float4 b4 = *(const float4*)&Bsh[d][4 * tx];
        float4 n4 = *(const float4*)&np_[(size_t)d * RR + 4 * tx];
        float4 o;
        o.x = fmaxf(b4.x * n4.x / (den[0] + EPSV), EPSV);
        o.y = fmaxf(b4.y * n4.y / (den[1] + EPSV), EPSV);
        o.z = fmaxf(b4.z * n4.z / (den[2] + EPSV), EPSV);
        o.w = fmaxf(b4.w * n4.w / (den[3] + EPSV), EPSV);
        *(float4*)&bp[(size_t)d * RR + 4 * tx] = o;
    }
}

// ---------------------------------------------------------------------------
// cfinal (r17-proven): fused compute_coef + x_hat; cin from cnb (coalesced).
// grid (NTOT/128, NB), 256 thr.
// ---------------------------------------------------------------------------
__global__ __launch_bounds__(256) void cfinal_kernel(const u16* __restrict__ xT,
                                                     const u16* __restrict__ bT,
                                                     const u16* __restrict__ btbbf,
                                                     const u16* __restrict__ cnb,
                                                     const u16* __restrict__ b_bf,
                                                     float* __restrict__ outp) {
    int s = blockIdx.y;
    int n0 = blockIdx.x * 128;
    int tid = threadIdx.x;
    int w = tid >> 6, lane = tid & 63, g = lane >> 4, l15 = lane & 15;
    int nw = n0 + w * 32;
    const u16* xTp = xT + (size_t)s * NTOT * DD;
    const u16* bTp = bT + (size_t)s * RR * DD;
    const u16* bb = btbbf + (size_t)s * RR * RR;
    const u16* cnp = cnb + (size_t)s * NTOT * RR;
    __shared__ __align__(16) u16 CL[128][72];

    f32x4 zero = {0.f, 0.f, 0.f, 0.f};
    f32x4 accD[4][2], accT[4][2];
#pragma unroll
    for (int rs = 0; rs < 4; ++rs)
#pragma unroll
        for (int ns = 0; ns < 2; ++ns) { accD[rs][ns] = zero; accT[rs][ns] = zero; }

#pragma unroll
    for (int k0 = 0; k0 < 64; k0 += 32) {
        bf16x8 a[4], b[2];
#pragma unroll
        for (int rs = 0; rs < 4; ++rs)
            a[rs] = *(const bf16x8*)&bb[(rs * 16 + l15) * RR + k0 + g * 8];
#pragma unroll
        for (int ns = 0; ns < 2; ++ns)
            b[ns] = *(const bf16x8*)&cnp[(size_t)(nw + ns * 16 + l15) * RR + k0 + g * 8];
#pragma unroll
        for (int rs = 0; rs < 4; ++rs)
#pragma unroll
            for (int ns = 0; ns < 2; ++ns)
                accD[rs][ns] = MFMA16(a[rs], b[ns], accD[rs][ns]);
    }
    {
        bf16x8 aA[4], bA[2], aB[4], bB[2];
#pragma unroll
        for (int rs = 0; rs < 4; ++rs)
            aA[rs] = *(const bf16x8*)&bTp[(rs * 16 + l15) * DD + g * 8];
#pragma unroll
        for (int ns = 0; ns < 2; ++ns)
            bA[ns] = clampbf8(*(const bf16x8*)&xTp[(size_t)(nw + ns * 16 + l15) * DD + g * 8]);
#pragma unroll
        for (int i = 0; i < 8; ++i) {
            int kB = i * 64 + 32;
#pragma unroll
            for (int rs = 0; rs < 4; ++rs)
                aB[rs] = *(const bf16x8*)&bTp[(rs * 16 + l15) * DD + kB + g * 8];
#pragma unroll
            for (int ns = 0; ns < 2; ++ns)
                bB[ns] = clampbf8(*(const bf16x8*)&xTp[(size_t)(nw + ns * 16 + l15) * DD + kB + g * 8]);
#pragma unroll
            for (int rs = 0; rs < 4; ++rs)
#pragma unroll
                for (int ns = 0; ns < 2; ++ns)
                    accT[rs][ns] = MFMA16(aA[rs], bA[ns], accT[rs][ns]);
            int kA = (i < 7) ? i * 64 + 64 : i * 64;
#pragma unroll
            for (int rs = 0; rs < 4; ++rs)
                aA[rs] = *(const bf16x8*)&bTp[(rs * 16 + l15) * DD + kA + g * 8];
#pragma unroll
            for (int ns = 0; ns < 2; ++ns)
                bA[ns] = clampbf8(*(const bf16x8*)&xTp[(size_t)(nw + ns * 16 + l15) * DD + kA + g * 8]);
#pragma unroll
            for (int rs = 0; rs < 4; ++rs)
#pragma unroll
                for (int ns = 0; ns < 2; ++ns)
                    accT[rs][ns] = MFMA16(aB[rs], bB[ns], accT[rs][ns]);
        }
    }
#pragma unroll
    for (int ns = 0; ns < 2; ++ns) {
        int n = nw + ns * 16 + l15;
        int nloc = w * 32 + ns * 16 + l15;
#pragma unroll
        for (int rs = 0; rs < 4; ++rs) {
            us4 cin4 = *(const us4*)&cnp[(size_t)n * RR + rs * 16 + g * 4];
            us4 pack;
#pragma unroll
            for (int e = 0; e < 4; ++e) {
                float cin = bf2f(cin4[e]);   // == clamp(coef) in bf16
                float v = cin * accT[rs][ns][e] / (accD[rs][ns][e] + EPSV);
                pack[e] = f2bf(v);
            }
            *(us4*)&CL[nloc][rs * 16 + g * 4] = pack;
        }
    }
    __syncthreads();
    bf16x8 bf_[8][2];
#pragma unroll
    for (int nf = 0; nf < 8; ++nf)
#pragma unroll
        for (int kc = 0; kc < 2; ++kc)
            bf_[nf][kc] = *(const bf16x8*)&CL[nf * 16 + l15][kc * 32 + g * 8];
    const u16* bbp = b_bf + (size_t)s * DD * RR;
    float* op = outp + (size_t)s * DD * NTOT;
#pragma unroll
    for (int df = 0; df < 8; ++df) {
        int d = w * 128 + df * 16 + l15;
        bf16x8 a0 = *(const bf16x8*)&bbp[d * RR + g * 8];
        bf16x8 a1 = *(const bf16x8*)&bbp[d * RR + 32 + g * 8];
        f32x4 acc[8];
#pragma unroll
        for (int nf = 0; nf < 8; ++nf) acc[nf] = zero;
#pragma unroll
        for (int nf = 0; nf < 8; ++nf) {
            acc[nf] = MFMA16(a0, bf_[nf][0], acc[nf]);
            acc[nf] = MFMA16(a1, bf_[nf][1], acc[nf]);
        }
#pragma unroll
        for (int nf = 0; nf < 8; ++nf)
#pragma unroll
            for (int e = 0; e < 4; ++e)
                op[(size_t)(w * 128 + df * 16 + g * 4 + e) * NTOT + n0 + nf * 16 + l15] =
                    acc[nf][e];
    }
}

// ---------------------------------------------------------------------------
extern "C" void kernel_launch(void* const* d_in, const int* in_sizes, int n_in,
                              void* d_out, int out_size, void* d_ws, size_t ws_size,
                              hipStream_t stream) {
    const float* x = (const float*)d_in[0];      // (2,512,65536) fp32
    const float* bases = (const float*)d_in[1];  // (2,512,64)
    float* out = (float*)d_out;
    char* ws = (char*)d_ws;

    // ws layout (~289 MB of the 1 GiB ws)
    u16* cTf = (u16*)ws;                            // @0          16,777,216
    u16* cnb = (u16*)(ws + 16777216);               // @16M        16,777,216
    u16* xTr = (u16*)(ws + 33554432);               // @32M       134,217,728
    u16* xd  = (u16*)(ws + 167772160);              // @160M      134,217,728
    float* b0 = (float*)(ws + 301989888);           // @288M         262,144
    float* ctc = (float*)(ws + 302252032);          //                32,768
    float* nB = (float*)(ws + 302284800);           //               262,144
    u16* b_bf = (u16*)(ws + 302546944);             //               131,072
    u16* bT_bf = (u16*)(ws + 302678016);            //               131,072
    u16* btb_bf = (u16*)(ws + 302809088);           //                16,384

    // 1) bf16 copies of x (xd clamped [d][n], xTr raw [n][d])
    convert_x_kernel<<<dim3(NTOT / 64, DD / 64, NB), 256, 0, stream>>>(x, xd, xTr);

    // 2) b = l2norm(bases) + casts + BtB; zeroes ctc/numB for step 0
    bnorm_kernel<<<NB, 1024, 0, stream>>>(bases, b0, b_bf, bT_bf, btb_bf, ctc, nB);

    // 3+4a) FUSED init softmax + MU step-0 c-update (one xTr pass)
    init2_mfma_kernel<<<dim3(NTOT / 128, NB), 256, 0, stream>>>(
        xTr, bT_bf, btb_bf, cnb, cTf);

    // 4) 6 MU steps, 4 dispatches each (r13-proven structure; xtb 64-tile)
    for (int step = 0; step < 6; ++step) {
        if (step > 0)
            xtb_mfma_kernel<<<dim3(NTOT / 64, NB), 256, 0, stream>>>(
                xTr, bT_bf, btb_bf, cnb, cTf);
        step_gemm_kernel<<<dim3(384, NB), 256, 0, stream>>>(xd, cTf, nB, ctc);
        bupd_s_kernel<<<dim3(8, NB), 256, 0, stream>>>(b0, nB, ctc);
        bnorm_kernel<<<NB, 1024, 0, stream>>>(b0, b0, b_bf, bT_bf, btb_bf, ctc, nB);
    }

    // 5+6) fused compute_coef + x_hat -> out
    cfinal_kernel<<<dim3(NTOT / 128, NB), 256, 0, stream>>>(
        xTr, bT_bf, btb_bf, cnb, b_bf, out);
}

// Round 19
// 1309.367 us; speedup vs baseline: 1.0737x; 1.0737x over previous
//
#include <hip/hip_runtime.h>
#include <math.h>

#define DD   512
#define NTOT 65536
#define RR   64
#define NB   2
#define EPSV 1e-6f

typedef unsigned short u16;
typedef __attribute__((ext_vector_type(8))) short bf16x8;
typedef __attribute__((ext_vector_type(8))) unsigned short us8;
typedef __attribute__((ext_vector_type(4))) unsigned short us4;
typedef __attribute__((ext_vector_type(4))) float f32x4;

__device__ inline u16 f2bf(float f) {
    union { float f; unsigned u; } x; x.f = f;
    unsigned r = x.u + 0x7FFFu + ((x.u >> 16) & 1u);   // RNE (no NaN here)
    return (u16)(r >> 16);
}
__device__ inline float bf2f(u16 h) {
    union { unsigned u; float f; } x; x.u = ((unsigned)h) << 16;
    return x.f;
}
__device__ inline u16 clamp1(u16 h) {
    short t = (short)h;
    return (u16)(t < (short)0x3586 ? (short)0x3586 : t);
}
__device__ inline bf16x8 clampbf8(bf16x8 v) {
#pragma unroll
    for (int i = 0; i < 8; ++i) {
        short t = v[i];
        v[i] = (t < (short)0x3586) ? (short)0x3586 : t;
    }
    return v;
}

#define MFMA16(a, b, c) __builtin_amdgcn_mfma_f32_16x16x32_bf16((a), (b), (c), 0, 0, 0)

// ---------------------------------------------------------------------------
// convert_x (r15-proven): x fp32 [s][d][n] -> xd bf16 clamped [s][d][n]
// (us4 stores) + xTr bf16 RAW [s][n][d]. grid (NTOT/64, DD/64, NB). Pad 66.
// ---------------------------------------------------------------------------
__global__ __launch_bounds__(256) void convert_x_kernel(const float* __restrict__ x,
                                                        u16* __restrict__ xd,
                                                        u16* __restrict__ xTr) {
    int s = blockIdx.z, d0 = blockIdx.y * 64, n0 = blockIdx.x * 64;
    const float* xp = x + ((size_t)s * DD + d0) * NTOT + n0;
    u16* xdp = xd + ((size_t)s * DD + d0) * NTOT + n0;
    u16* xtr = xTr + ((size_t)s * NTOT + n0) * DD + d0;
    __shared__ u16 L[64][66];
    int tid = threadIdx.x;
#pragma unroll
    for (int k = 0; k < 4; ++k) {
        int f4 = tid + k * 256;
        int dr = f4 >> 4, c4 = (f4 & 15) * 4;
        float4 v = *(const float4*)&xp[(size_t)dr * NTOT + c4];
        u16 h0 = f2bf(v.x), h1 = f2bf(v.y), h2 = f2bf(v.z), h3 = f2bf(v.w);
        us4 pc;
        pc[0] = clamp1(h0); pc[1] = clamp1(h1);
        pc[2] = clamp1(h2); pc[3] = clamp1(h3);
        *(us4*)&xdp[(size_t)dr * NTOT + c4] = pc;
        L[dr][c4 + 0] = h0; L[dr][c4 + 1] = h1;
        L[dr][c4 + 2] = h2; L[dr][c4 + 3] = h3;
    }
    __syncthreads();
#pragma unroll
    for (int k = 0; k < 2; ++k) {
        int f8 = tid + k * 256;
        int nr = f8 >> 3, d8 = (f8 & 7) * 8;
        us8 wr;
#pragma unroll
        for (int i = 0; i < 8; ++i) wr[i] = L[d8 + i][nr];
        *(us8*)&xtr[(size_t)nr * DD + d8] = wr;
    }
}

// ---------------------------------------------------------------------------
// bnorm (r13-proven + zero duty): per batch, column-l2-normalize src -> b0,
// b_bf, bT_bf, BtB (MFMA gram); also zeroes ctc+numB for the next step.
// grid (NB), 1024 thr.
// ---------------------------------------------------------------------------
__global__ __launch_bounds__(1024) void bnorm_kernel(const float* __restrict__ src,
                                                     float* __restrict__ b0,
                                                     u16* __restrict__ b_bf,
                                                     u16* __restrict__ bT_bf,
                                                     u16* __restrict__ btb_bf,
                                                     float* __restrict__ ctcZ,
                                                     float* __restrict__ nBZ) {
    int s = blockIdx.x, tid = threadIdx.x;
    int r = tid & 63, grp = tid >> 6;
    const float* sp = src + (size_t)s * DD * RR;
    float* b0p = b0 + (size_t)s * DD * RR;
    u16* bbp = b_bf + (size_t)s * DD * RR;
    {
        float4 z4 = {0.f, 0.f, 0.f, 0.f};
        float* zc = ctcZ + (size_t)s * RR * RR;
        float* zn = nBZ + (size_t)s * DD * RR;
        *(float4*)&zc[tid * 4] = z4;
#pragma unroll
        for (int k = 0; k < 8; ++k)
            *(float4*)&zn[(tid + k * 1024) * 4] = z4;
    }
    __shared__ float part[16][64];
    __shared__ float invl[64];
    __shared__ __align__(16) u16 btl[64][520];
    float vv[32];
    float p = 0.f;
#pragma unroll
    for (int i = 0; i < 32; ++i) {
        vv[i] = sp[(grp * 32 + i) * 64 + r];
        p += vv[i] * vv[i];
    }
    part[grp][r] = p;
    __syncthreads();
    if (tid < 64) {
        float ss = 0.f;
#pragma unroll
        for (int k = 0; k < 16; ++k) ss += part[k][tid];
        invl[tid] = 1.f / fmaxf(sqrtf(ss), 1e-12f);
    }
    __syncthreads();
    float inv = invl[r];
#pragma unroll
    for (int i = 0; i < 32; ++i) {
        int d = grp * 32 + i;
        float v = vv[i] * inv;
        b0p[d * 64 + r] = v;
        u16 h = f2bf(v);
        bbp[d * 64 + r] = h;
        btl[r][d] = h;
    }
    __syncthreads();
    u16* btg = bT_bf + (size_t)s * RR * DD;
#pragma unroll
    for (int k = 0; k < 4; ++k) {
        int f8 = tid + k * 1024;
        int row = f8 >> 6, c8 = (f8 & 63) * 8;
        *(us8*)&btg[row * DD + c8] = *(const us8*)&btl[row][c8];
    }
    if (grp < 4) {
        int g = r >> 4, l15 = r & 15;
        f32x4 zero = {0.f, 0.f, 0.f, 0.f};
        f32x4 acc[4];
#pragma unroll
        for (int cs = 0; cs < 4; ++cs) acc[cs] = zero;
        for (int k0 = 0; k0 < DD; k0 += 32) {
            bf16x8 a = *(const bf16x8*)&btl[grp * 16 + l15][k0 + g * 8];
            bf16x8 b[4];
#pragma unroll
            for (int cs = 0; cs < 4; ++cs)
                b[cs] = *(const bf16x8*)&btl[cs * 16 + l15][k0 + g * 8];
#pragma unroll
            for (int cs = 0; cs < 4; ++cs) acc[cs] = MFMA16(a, b[cs], acc[cs]);
        }
        u16* op = btb_bf + (size_t)s * RR * RR;
#pragma unroll
        for (int cs = 0; cs < 4; ++cs)
#pragma unroll
            for (int e = 0; e < 4; ++e)
                op[(grp * 16 + g * 4 + e) * RR + cs * 16 + l15] = f2bf(acc[cs][e]);
    }
}

// ---------------------------------------------------------------------------
// init2_mfma (r17-proven): FUSED init-softmax + step 0, coalesced cTf write.
// grid (NTOT/128, NB), 256 thr.
// ---------------------------------------------------------------------------
__global__ __launch_bounds__(256) void init2_mfma_kernel(const u16* __restrict__ xT,
                                                         const u16* __restrict__ bT,
                                                         const u16* __restrict__ btbbf,
                                                         u16* __restrict__ cnb,
                                                         u16* __restrict__ cT) {
    int s = blockIdx.y;
    int n0 = blockIdx.x * 128;
    int tid = threadIdx.x;
    int w = tid >> 6, lane = tid & 63, g = lane >> 4, l15 = lane & 15;
    int nw = n0 + w * 32;
    const u16* xTp = xT + (size_t)s * NTOT * DD;
    const u16* bTp = bT + (size_t)s * RR * DD;
    const u16* bb = btbbf + (size_t)s * RR * RR;
    u16* cnp = cnb + (size_t)s * NTOT * RR;
    u16* cTp = cT + (size_t)s * RR * NTOT;
    __shared__ __align__(16) u16 CL[128][72];
    __shared__ __align__(16) u16 TL[64][132];

    f32x4 zero = {0.f, 0.f, 0.f, 0.f};
    f32x4 accR[4][2], accC[4][2];
#pragma unroll
    for (int rs = 0; rs < 4; ++rs)
#pragma unroll
        for (int ns = 0; ns < 2; ++ns) { accR[rs][ns] = zero; accC[rs][ns] = zero; }

    {
        bf16x8 aA[4], bA[2], aB[4], bB[2];
#pragma unroll
        for (int rs = 0; rs < 4; ++rs)
            aA[rs] = *(const bf16x8*)&bTp[(rs * 16 + l15) * DD + g * 8];
#pragma unroll
        for (int ns = 0; ns < 2; ++ns)
            bA[ns] = *(const bf16x8*)&xTp[(size_t)(nw + ns * 16 + l15) * DD + g * 8];
#pragma unroll
        for (int i = 0; i < 8; ++i) {
            int kB = i * 64 + 32;
#pragma unroll
            for (int rs = 0; rs < 4; ++rs)
                aB[rs] = *(const bf16x8*)&bTp[(rs * 16 + l15) * DD + kB + g * 8];
#pragma unroll
            for (int ns = 0; ns < 2; ++ns)
                bB[ns] = *(const bf16x8*)&xTp[(size_t)(nw + ns * 16 + l15) * DD + kB + g * 8];
#pragma unroll
            for (int ns = 0; ns < 2; ++ns) {
                bf16x8 bc = clampbf8(bA[ns]);
#pragma unroll
                for (int rs = 0; rs < 4; ++rs) {
                    accR[rs][ns] = MFMA16(aA[rs], bA[ns], accR[rs][ns]);
                    accC[rs][ns] = MFMA16(aA[rs], bc, accC[rs][ns]);
                }
            }
            int kA = (i < 7) ? i * 64 + 64 : i * 64;
#pragma unroll
            for (int rs = 0; rs < 4; ++rs)
                aA[rs] = *(const bf16x8*)&bTp[(rs * 16 + l15) * DD + kA + g * 8];
#pragma unroll
            for (int ns = 0; ns < 2; ++ns)
                bA[ns] = *(const bf16x8*)&xTp[(size_t)(nw + ns * 16 + l15) * DD + kA + g * 8];
#pragma unroll
            for (int ns = 0; ns < 2; ++ns) {
                bf16x8 bc = clampbf8(bB[ns]);
#pragma unroll
                for (int rs = 0; rs < 4; ++rs) {
                    accR[rs][ns] = MFMA16(aB[rs], bB[ns], accR[rs][ns]);
                    accC[rs][ns] = MFMA16(aB[rs], bc, accC[rs][ns]);
                }
            }
        }
    }

#pragma unroll
    for (int ns = 0; ns < 2; ++ns) {
        int nloc = w * 32 + ns * 16 + l15;
        float m = accR[0][ns][0];
#pragma unroll
        for (int rs = 0; rs < 4; ++rs)
#pragma unroll
            for (int e = 0; e < 4; ++e) m = fmaxf(m, accR[rs][ns][e]);
        m = fmaxf(m, __shfl_xor(m, 16));
        m = fmaxf(m, __shfl_xor(m, 32));
        float ev[4][4];
        float ssum = 0.f;
#pragma unroll
        for (int rs = 0; rs < 4; ++rs)
#pragma unroll
            for (int e = 0; e < 4; ++e) {
                ev[rs][e] = __expf(accR[rs][ns][e] - m);
                ssum += ev[rs][e];
            }
        ssum += __shfl_xor(ssum, 16);
        ssum += __shfl_xor(ssum, 32);
        float inv = 1.f / ssum;
#pragma unroll
        for (int rs = 0; rs < 4; ++rs) {
            us4 pack;
#pragma unroll
            for (int e = 0; e < 4; ++e) pack[e] = f2bf(ev[rs][e] * inv);
            *(us4*)&CL[nloc][rs * 16 + g * 4] = pack;
        }
    }
    __syncthreads();

    f32x4 accD[4][2];
#pragma unroll
    for (int rs = 0; rs < 4; ++rs)
#pragma unroll
        for (int ns = 0; ns < 2; ++ns) accD[rs][ns] = zero;
#pragma unroll
    for (int k0 = 0; k0 < 64; k0 += 32) {
        bf16x8 a[4], b[2];
#pragma unroll
        for (int rs = 0; rs < 4; ++rs)
            a[rs] = *(const bf16x8*)&bb[(rs * 16 + l15) * RR + k0 + g * 8];
#pragma unroll
        for (int ns = 0; ns < 2; ++ns)
            b[ns] = *(const bf16x8*)&CL[w * 32 + ns * 16 + l15][k0 + g * 8];
#pragma unroll
        for (int rs = 0; rs < 4; ++rs)
#pragma unroll
            for (int ns = 0; ns < 2; ++ns)
                accD[rs][ns] = MFMA16(a[rs], b[ns], accD[rs][ns]);
    }

#pragma unroll
    for (int ns = 0; ns < 2; ++ns) {
        int n = nw + ns * 16 + l15;
        int nloc = w * 32 + ns * 16 + l15;
#pragma unroll
        for (int rs = 0; rs < 4; ++rs) {
            us4 cf4 = *(const us4*)&CL[nloc][rs * 16 + g * 4];
            us4 pack;
#pragma unroll
            for (int e = 0; e < 4; ++e) {
                int r = rs * 16 + g * 4 + e;
                float cin = bf2f(cf4[e]);
                float v = cin * accC[rs][ns][e] / (accD[rs][ns][e] + EPSV);
                u16 h = f2bf(v);
                TL[r][nloc] = h;
                pack[e] = clamp1(h);
            }
            *(us4*)&cnp[(size_t)n * RR + rs * 16 + g * 4] = pack;
        }
    }
    __syncthreads();
#pragma unroll
    for (int k = 0; k < 4; ++k) {
        int f8 = tid + k * 256;
        int row = f8 >> 4, c8 = (f8 & 15) * 8;
        *(us8*)&cTp[(size_t)row * NTOT + n0 + c8] = *(const us8*)&TL[row][c8];
    }
}

// ---------------------------------------------------------------------------
// xtb_mfma (r17-proven, 128-tile): den = BtB@cnb; T = bT@clamp(x);
// c = cnb*T/(den+EPS) -> TL->cTf (coalesced) and clamped cnb.
// grid (NTOT/128, NB), 256 thr.
// ---------------------------------------------------------------------------
__global__ __launch_bounds__(256) void xtb_mfma_kernel(const u16* __restrict__ xT,
                                                       const u16* __restrict__ bT,
                                                       const u16* __restrict__ btbbf,
                                                       u16* __restrict__ cnb,
                                                       u16* __restrict__ cT) {
    int s = blockIdx.y;
    int n0 = blockIdx.x * 128;
    int tid = threadIdx.x;
    int w = tid >> 6, lane = tid & 63, g = lane >> 4, l15 = lane & 15;
    int nw = n0 + w * 32;
    const u16* xTp = xT + (size_t)s * NTOT * DD;
    const u16* bTp = bT + (size_t)s * RR * DD;
    const u16* bb = btbbf + (size_t)s * RR * RR;
    u16* cnp = cnb + (size_t)s * NTOT * RR;
    u16* cTp = cT + (size_t)s * RR * NTOT;
    __shared__ __align__(16) u16 TL[64][132];   // c-tile [r][n_local]

    f32x4 zero = {0.f, 0.f, 0.f, 0.f};
    f32x4 accD[4][2], accT[4][2];
#pragma unroll
    for (int rs = 0; rs < 4; ++rs)
#pragma unroll
        for (int ns = 0; ns < 2; ++ns) { accD[rs][ns] = zero; accT[rs][ns] = zero; }

#pragma unroll
    for (int k0 = 0; k0 < 64; k0 += 32) {
        bf16x8 a[4], b[2];
#pragma unroll
        for (int rs = 0; rs < 4; ++rs)
            a[rs] = *(const bf16x8*)&bb[(rs * 16 + l15) * RR + k0 + g * 8];
#pragma unroll
        for (int ns = 0; ns < 2; ++ns)
            b[ns] = *(const bf16x8*)&cnp[(size_t)(nw + ns * 16 + l15) * RR + k0 + g * 8];
#pragma unroll
        for (int rs = 0; rs < 4; ++rs)
#pragma unroll
            for (int ns = 0; ns < 2; ++ns)
                accD[rs][ns] = MFMA16(a[rs], b[ns], accD[rs][ns]);
    }

    {
        bf16x8 aA[4], bA[2], aB[4], bB[2];
#pragma unroll
        for (int rs = 0; rs < 4; ++rs)
            aA[rs] = *(const bf16x8*)&bTp[(rs * 16 + l15) * DD + g * 8];
#pragma unroll
        for (int ns = 0; ns < 2; ++ns)
            bA[ns] = clampbf8(*(const bf16x8*)&xTp[(size_t)(nw + ns * 16 + l15) * DD + g * 8]);
#pragma unroll
        for (int i = 0; i < 8; ++i) {
            int kB = i * 64 + 32;
#pragma unroll
            for (int rs = 0; rs < 4; ++rs)
                aB[rs] = *(const bf16x8*)&bTp[(rs * 16 + l15) * DD + kB + g * 8];
#pragma unroll
            for (int ns = 0; ns < 2; ++ns)
                bB[ns] = clampbf8(*(const bf16x8*)&xTp[(size_t)(nw + ns * 16 + l15) * DD + kB + g * 8]);
#pragma unroll
            for (int rs = 0; rs < 4; ++rs)
#pragma unroll
                for (int ns = 0; ns < 2; ++ns)
                    accT[rs][ns] = MFMA16(aA[rs], bA[ns], accT[rs][ns]);
            int kA = (i < 7) ? i * 64 + 64 : i * 64;
#pragma unroll
            for (int rs = 0; rs < 4; ++rs)
                aA[rs] = *(const bf16x8*)&bTp[(rs * 16 + l15) * DD + kA + g * 8];
#pragma unroll
            for (int ns = 0; ns < 2; ++ns)
                bA[ns] = clampbf8(*(const bf16x8*)&xTp[(size_t)(nw + ns * 16 + l15) * DD + kA + g * 8]);
#pragma unroll
            for (int rs = 0; rs < 4; ++rs)
#pragma unroll
                for (int ns = 0; ns < 2; ++ns)
                    accT[rs][ns] = MFMA16(aB[rs], bB[ns], accT[rs][ns]);
        }
    }

    // epilogue: cin from cnb (coalesced us4); c -> TL + clamped cnb.
#pragma unroll
    for (int ns = 0; ns < 2; ++ns) {
        int n = nw + ns * 16 + l15;
        int nloc = w * 32 + ns * 16 + l15;
#pragma unroll
        for (int rs = 0; rs < 4; ++rs) {
            us4 cin4 = *(const us4*)&cnp[(size_t)n * RR + rs * 16 + g * 4];
            us4 pack;
#pragma unroll
            for (int e = 0; e < 4; ++e) {
                int r = rs * 16 + g * 4 + e;
                float cin = bf2f(cin4[e]);
                float v = cin * accT[rs][ns][e] / (accD[rs][ns][e] + EPSV);
                u16 h = f2bf(v);
                TL[r][nloc] = h;
                pack[e] = clamp1(h);   // v>0 so clamp = max
            }
            *(us4*)&cnp[(size_t)n * RR + rs * 16 + g * 4] = pack;
        }
    }
    __syncthreads();
#pragma unroll
    for (int k = 0; k < 4; ++k) {
        int f8 = tid + k * 256;
        int row = f8 >> 4, c8 = (f8 & 15) * 8;
        *(us8*)&cTp[(size_t)row * NTOT + n0 + c8] = *(const us8*)&TL[row][c8];
    }
}

// ---------------------------------------------------------------------------
// step_gemm (r12-proven): dual-role packed dispatch. Blocks 0..255 = xtc body
// (ksplit 32, chunk 2048); blocks 256..383 = ctc body (chunk 512).
// grid (384, NB), 256 thr.
// ---------------------------------------------------------------------------
__global__ __launch_bounds__(256) void step_gemm_kernel(const u16* __restrict__ xd,
                                                        const u16* __restrict__ cT,
                                                        float* __restrict__ numB,
                                                        float* __restrict__ ctc) {
    int s = blockIdx.y;
    int bid = blockIdx.x;
    int tid = threadIdx.x;
    int w = tid >> 6, lane = tid & 63, g = lane >> 4, l15 = lane & 15;
    const u16* cTp = cT + (size_t)s * RR * NTOT;
    f32x4 zero = {0.f, 0.f, 0.f, 0.f};

    if (bid < 256) {
        int kbase = (bid >> 3) * 2048;
        int dtile = (bid & 7) * 64;
        const u16* arow =
            xd + (size_t)s * DD * NTOT + (size_t)(dtile + w * 16 + l15) * NTOT;
        f32x4 acc[4];
#pragma unroll
        for (int rs = 0; rs < 4; ++rs) acc[rs] = zero;

        bf16x8 aA, bA[4], aB, bB[4];
        aA = *(const bf16x8*)&arow[kbase + g * 8];
#pragma unroll
        for (int rs = 0; rs < 4; ++rs)
            bA[rs] = *(const bf16x8*)&cTp[(size_t)(rs * 16 + l15) * NTOT + kbase + g * 8];
#pragma unroll
        for (int i = 0; i < 32; ++i) {
            int kB = kbase + i * 64 + 32;
            aB = *(const bf16x8*)&arow[kB + g * 8];
#pragma unroll
            for (int rs = 0; rs < 4; ++rs)
                bB[rs] = *(const bf16x8*)&cTp[(size_t)(rs * 16 + l15) * NTOT + kB + g * 8];
#pragma unroll
            for (int rs = 0; rs < 4; ++rs) acc[rs] = MFMA16(aA, bA[rs], acc[rs]);
            int kA = (i < 31) ? kbase + i * 64 + 64 : kbase;
            aA = *(const bf16x8*)&arow[kA + g * 8];
#pragma unroll
            for (int rs = 0; rs < 4; ++rs)
                bA[rs] = *(const bf16x8*)&cTp[(size_t)(rs * 16 + l15) * NTOT + kA + g * 8];
#pragma unroll
            for (int rs = 0; rs < 4; ++rs) acc[rs] = MFMA16(aB, bB[rs], acc[rs]);
        }
        float* op = numB + (size_t)s * DD * RR;
#pragma unroll
        for (int rs = 0; rs < 4; ++rs)
#pragma unroll
            for (int e = 0; e < 4; ++e)
                atomicAdd(&op[(dtile + w * 16 + g * 4 + e) * RR + rs * 16 + l15],
                          acc[rs][e]);
    } else {
        int kbase = (bid - 256) * 512;
        const u16* arow = cTp + (size_t)(w * 16 + l15) * NTOT;
        f32x4 acc[4];
#pragma unroll
        for (int cs = 0; cs < 4; ++cs) acc[cs] = zero;

        bf16x8 aA, bA[4], aB, bB[4];
        aA = *(const bf16x8*)&arow[kbase + g * 8];
#pragma unroll
        for (int cs = 0; cs < 4; ++cs)
            bA[cs] = *(const bf16x8*)&cTp[(size_t)(cs * 16 + l15) * NTOT + kbase + g * 8];
#pragma unroll
        for (int i = 0; i < 8; ++i) {
            int kB = kbase + i * 64 + 32;
            aB = *(const bf16x8*)&arow[kB + g * 8];
#pragma unroll
            for (int cs = 0; cs < 4; ++cs)
                bB[cs] = *(const bf16x8*)&cTp[(size_t)(cs * 16 + l15) * NTOT + kB + g * 8];
#pragma unroll
            for (int cs = 0; cs < 4; ++cs) acc[cs] = MFMA16(aA, bA[cs], acc[cs]);
            int kA = (i < 7) ? kbase + i * 64 + 64 : kbase;
            aA = *(const bf16x8*)&arow[kA + g * 8];
#pragma unroll
            for (int cs = 0; cs < 4; ++cs)
                bA[cs] = *(const bf16x8*)&cTp[(size_t)(cs * 16 + l15) * NTOT + kA + g * 8];
#pragma unroll
            for (int cs = 0; cs < 4; ++cs) acc[cs] = MFMA16(aB, bB[cs], acc[cs]);
        }
        float* op = ctc + (size_t)s * RR * RR;
#pragma unroll
        for (int cs = 0; cs < 4; ++cs)
#pragma unroll
            for (int e = 0; e < 4; ++e)
                atomicAdd(&op[(w * 16 + g * 4 + e) * RR + cs * 16 + l15], acc[cs][e]);
    }
}

// ---------------------------------------------------------------------------
// bupd_s (proven): b0 = max(b0*numB/(b0@CtC+EPS), EPS) in-place.
// grid (8, NB), 256 thr.
// ---------------------------------------------------------------------------
__global__ __launch_bounds__(256) void bupd_s_kernel(float* __restrict__ b0,
                                                     const float* __restrict__ numB,
                                                     const float* __restrict__ ctcG) {
    int s = blockIdx.y;
    int d0 = blockIdx.x * 64;
    float* bp = b0 + ((size_t)s * DD + d0) * RR;
    const float* np_ = numB + ((size_t)s * DD + d0) * RR;
    const float* cc = ctcG + (size_t)s * RR * RR;
    __shared__ __align__(16) float Bsh[64][68];
    __shared__ __align__(16) float Ct[64][68];
    int tid = threadIdx.x, tx = tid & 15, ty = tid >> 4;
#pragma unroll
    for (int k = 0; k < 16; ++k) {
        int idx = tid + k * 256;
        int r_ = idx >> 6, col = idx & 63;
        Bsh[r_][col] = bp[idx];
        Ct[r_][col] = cc[idx];
    }
    __syncthreads();
#pragma unroll
    for (int i = 0; i < 4; ++i) {
        int d = 4 * ty + i;
        float den[4] = {};
#pragma unroll
        for (int k = 0; k < 64; ++k) {
            float bv = Bsh[d][k];
            float4 ct = *(const float4*)&Ct[k][4 * tx];
            den[0] += bv * ct.x;
            den[1] += bv * ct.y;
            den[2] += bv * ct.z;
            den[3] += bv * ct.w;
        }
        float4 b4 = *(const float4*)&Bsh[d][4 * tx];
        float4 n4 = *(const float4*)&np_[(size_t)d * RR + 4 * tx];
        float4 o;
        o.x = fmaxf(b4.x * n4.x / (den[0] + EPSV), EPSV);
        o.y = fmaxf(b4.y * n4.y / (den[1] + EPSV), EPSV);
        o.z = fmaxf(b4.z * n4.z / (den[2] + EPSV), EPSV);
        o.w = fmaxf(b4.w * n4.w / (den[3] + EPSV), EPSV);
        *(float4*)&bp[(size_t)d * RR + 4 * tx] = o;
    }
}

// ---------------------------------------------------------------------------
// cfinal (r17-proven): fused compute_coef + x_hat; cin from cnb (coalesced).
// grid (NTOT/128, NB), 256 thr.
// ---------------------------------------------------------------------------
__global__ __launch_bounds__(256) void cfinal_kernel(const u16* __restrict__ xT,
                                                     const u16* __restrict__ bT,
                                                     const u16* __restrict__ btbbf,
                                                     const u16* __restrict__ cnb,
                                                     const u16* __restrict__ b_bf,
                                                     float* __restrict__ outp) {
    int s = blockIdx.y;
    int n0 = blockIdx.x * 128;
    int tid = threadIdx.x;
    int w = tid >> 6, lane = tid & 63, g = lane >> 4, l15 = lane & 15;
    int nw = n0 + w * 32;
    const u16* xTp = xT + (size_t)s * NTOT * DD;
    const u16* bTp = bT + (size_t)s * RR * DD;
    const u16* bb = btbbf + (size_t)s * RR * RR;
    const u16* cnp = cnb + (size_t)s * NTOT * RR;
    __shared__ __align__(16) u16 CL[128][72];

    f32x4 zero = {0.f, 0.f, 0.f, 0.f};
    f32x4 accD[4][2], accT[4][2];
#pragma unroll
    for (int rs = 0; rs < 4; ++rs)
#pragma unroll
        for (int ns = 0; ns < 2; ++ns) { accD[rs][ns] = zero; accT[rs][ns] = zero; }

#pragma unroll
    for (int k0 = 0; k0 < 64; k0 += 32) {
        bf16x8 a[4], b[2];
#pragma unroll
        for (int rs = 0; rs < 4; ++rs)
            a[rs] = *(const bf16x8*)&bb[(rs * 16 + l15) * RR + k0 + g * 8];
#pragma unroll
        for (int ns = 0; ns < 2; ++ns)
            b[ns] = *(const bf16x8*)&cnp[(size_t)(nw + ns * 16 + l15) * RR + k0 + g * 8];
#pragma unroll
        for (int rs = 0; rs < 4; ++rs)
#pragma unroll
            for (int ns = 0; ns < 2; ++ns)
                accD[rs][ns] = MFMA16(a[rs], b[ns], accD[rs][ns]);
    }
    {
        bf16x8 aA[4], bA[2], aB[4], bB[2];
#pragma unroll
        for (int rs = 0; rs < 4; ++rs)
            aA[rs] = *(const bf16x8*)&bTp[(rs * 16 + l15) * DD + g * 8];
#pragma unroll
        for (int ns = 0; ns < 2; ++ns)
            bA[ns] = clampbf8(*(const bf16x8*)&xTp[(size_t)(nw + ns * 16 + l15) * DD + g * 8]);
#pragma unroll
        for (int i = 0; i < 8; ++i) {
            int kB = i * 64 + 32;
#pragma unroll
            for (int rs = 0; rs < 4; ++rs)
                aB[rs] = *(const bf16x8*)&bTp[(rs * 16 + l15) * DD + kB + g * 8];
#pragma unroll
            for (int ns = 0; ns < 2; ++ns)
                bB[ns] = clampbf8(*(const bf16x8*)&xTp[(size_t)(nw + ns * 16 + l15) * DD + kB + g * 8]);
#pragma unroll
            for (int rs = 0; rs < 4; ++rs)
#pragma unroll
                for (int ns = 0; ns < 2; ++ns)
                    accT[rs][ns] = MFMA16(aA[rs], bA[ns], accT[rs][ns]);
            int kA = (i < 7) ? i * 64 + 64 : i * 64;
#pragma unroll
            for (int rs = 0; rs < 4; ++rs)
                aA[rs] = *(const bf16x8*)&bTp[(rs * 16 + l15) * DD + kA + g * 8];
#pragma unroll
            for (int ns = 0; ns < 2; ++ns)
                bA[ns] = clampbf8(*(const bf16x8*)&xTp[(size_t)(nw + ns * 16 + l15) * DD + kA + g * 8]);
#pragma unroll
            for (int rs = 0; rs < 4; ++rs)
#pragma unroll
                for (int ns = 0; ns < 2; ++ns)
                    accT[rs][ns] = MFMA16(aB[rs], bB[ns], accT[rs][ns]);
        }
    }
#pragma unroll
    for (int ns = 0; ns < 2; ++ns) {
        int n = nw + ns * 16 + l15;
        int nloc = w * 32 + ns * 16 + l15;
#pragma unroll
        for (int rs = 0; rs < 4; ++rs) {
            us4 cin4 = *(const us4*)&cnp[(size_t)n * RR + rs * 16 + g * 4];
            us4 pack;
#pragma unroll
            for (int e = 0; e < 4; ++e) {
                float cin = bf2f(cin4[e]);   // == clamp(coef) in bf16
                float v = cin * accT[rs][ns][e] / (accD[rs][ns][e] + EPSV);
                pack[e] = f2bf(v);
            }
            *(us4*)&CL[nloc][rs * 16 + g * 4] = pack;
        }
    }
    __syncthreads();
    bf16x8 bf_[8][2];
#pragma unroll
    for (int nf = 0; nf < 8; ++nf)
#pragma unroll
        for (int kc = 0; kc < 2; ++kc)
            bf_[nf][kc] = *(const bf16x8*)&CL[nf * 16 + l15][kc * 32 + g * 8];
    const u16* bbp = b_bf + (size_t)s * DD * RR;
    float* op = outp + (size_t)s * DD * NTOT;
#pragma unroll
    for (int df = 0; df < 8; ++df) {
        int d = w * 128 + df * 16 + l15;
        bf16x8 a0 = *(const bf16x8*)&bbp[d * RR + g * 8];
        bf16x8 a1 = *(const bf16x8*)&bbp[d * RR + 32 + g * 8];
        f32x4 acc[8];
#pragma unroll
        for (int nf = 0; nf < 8; ++nf) acc[nf] = zero;
#pragma unroll
        for (int nf = 0; nf < 8; ++nf) {
            acc[nf] = MFMA16(a0, bf_[nf][0], acc[nf]);
            acc[nf] = MFMA16(a1, bf_[nf][1], acc[nf]);
        }
#pragma unroll
        for (int nf = 0; nf < 8; ++nf)
#pragma unroll
            for (int e = 0; e < 4; ++e)
                op[(size_t)(w * 128 + df * 16 + g * 4 + e) * NTOT + n0 + nf * 16 + l15] =
                    acc[nf][e];
    }
}

// ---------------------------------------------------------------------------
extern "C" void kernel_launch(void* const* d_in, const int* in_sizes, int n_in,
                              void* d_out, int out_size, void* d_ws, size_t ws_size,
                              hipStream_t stream) {
    const float* x = (const float*)d_in[0];      // (2,512,65536) fp32
    const float* bases = (const float*)d_in[1];  // (2,512,64)
    float* out = (float*)d_out;
    char* ws = (char*)d_ws;

    // ws layout (~289 MB of the 1 GiB ws)
    u16* cTf = (u16*)ws;                            // @0          16,777,216
    u16* cnb = (u16*)(ws + 16777216);               // @16M        16,777,216
    u16* xTr = (u16*)(ws + 33554432);               // @32M       134,217,728
    u16* xd  = (u16*)(ws + 167772160);              // @160M      134,217,728
    float* b0 = (float*)(ws + 301989888);           // @288M         262,144
    float* ctc = (float*)(ws + 302252032);          //                32,768
    float* nB = (float*)(ws + 302284800);           //               262,144
    u16* b_bf = (u16*)(ws + 302546944);             //               131,072
    u16* bT_bf = (u16*)(ws + 302678016);            //               131,072
    u16* btb_bf = (u16*)(ws + 302809088);           //                16,384

    // 1) bf16 copies of x (xd clamped [d][n], xTr raw [n][d])
    convert_x_kernel<<<dim3(NTOT / 64, DD / 64, NB), 256, 0, stream>>>(x, xd, xTr);

    // 2) b = l2norm(bases) + casts + BtB; zeroes ctc/numB for step 0
    bnorm_kernel<<<NB, 1024, 0, stream>>>(bases, b0, b_bf, bT_bf, btb_bf, ctc, nB);

    // 3+4a) FUSED init softmax + MU step-0 c-update (one xTr pass)
    init2_mfma_kernel<<<dim3(NTOT / 128, NB), 256, 0, stream>>>(
        xTr, bT_bf, btb_bf, cnb, cTf);

    // 4) 6 MU steps, 4 dispatches each (r17-proven structure)
    for (int step = 0; step < 6; ++step) {
        if (step > 0)
            xtb_mfma_kernel<<<dim3(NTOT / 128, NB), 256, 0, stream>>>(
                xTr, bT_bf, btb_bf, cnb, cTf);
        step_gemm_kernel<<<dim3(384, NB), 256, 0, stream>>>(xd, cTf, nB, ctc);
        bupd_s_kernel<<<dim3(8, NB), 256, 0, stream>>>(b0, nB, ctc);
        bnorm_kernel<<<NB, 1024, 0, stream>>>(b0, b0, b_bf, bT_bf, btb_bf, ctc, nB);
    }

    // 5+6) fused compute_coef + x_hat -> out
    cfinal_kernel<<<dim3(NTOT / 128, NB), 256, 0, stream>>>(
        xTr, bT_bf, btb_bf, cnb, b_bf, out);
}